// Round 1
// baseline (48474.274 us; speedup 1.0000x reference)
//
#include <hip/hip_runtime.h>
#include <math.h>

// Problem dims
#define BB 512     // batch
#define HH 512     // hidden
#define SS 256     // seq len
#define XD0 3      // layer0 input dim
#define TDN 256    // td output dim
#define FC1N 20
#define OUTN 2

// Tiles
#define TM 32
#define TN 32
#define TK 32

__device__ __forceinline__ float sigmoid_(float x) {
    return 1.0f / (1.0f + __expf(-x));
}
__device__ __forceinline__ float tanh_(float x) {
    // tanh(x) = 1 - 2/(e^{2x}+1); saturates correctly for |x| large
    float e = __expf(2.0f * x);
    return 1.0f - 2.0f / (e + 1.0f);
}

// Accumulate acc[4][4] += A_tile @ W_tile^T over K=HH, staged through LDS.
// A: [BB, HH] row-major, rows r0..r0+31.
// W: [4*HH, HH] row-major, rows g*HH + j0 + j (g=0..3, j=0..31).
// Thread t: jl = t&31 (j), rg = t>>5 (row group, 4 rows each), acc[rr][g].
__device__ __forceinline__ void gemm_pass(
    const float* __restrict__ A, const float* __restrict__ W,
    int r0, int j0, int t,
    float (&acc)[4][4],
    float (*a_lds)[TK + 1],          // [TM][TK+1]
    float (*w_lds)[TN][TK + 1])      // [4][TN][TK+1]
{
    const int jl = t & 31;
    const int rg = t >> 5;
    for (int k0 = 0; k0 < HH; k0 += TK) {
        // stage A tile: a_lds[r][kk] = A[r0+r][k0+kk]  (coalesced over kk)
        #pragma unroll
        for (int i = 0; i < (TM * TK) / 256; ++i) {
            int idx = t + i * 256;
            int r = idx >> 5, kk = idx & 31;
            a_lds[r][kk] = A[(size_t)(r0 + r) * HH + k0 + kk];
        }
        // stage W tile: w_lds[g][j][kk] = W[(g*HH + j0 + j)][k0+kk]
        #pragma unroll
        for (int i = 0; i < (4 * TN * TK) / 256; ++i) {
            int idx = t + i * 256;
            int g = idx >> 10;
            int j = (idx >> 5) & 31;
            int kk = idx & 31;
            w_lds[g][j][kk] = W[(size_t)(g * HH + j0 + j) * HH + k0 + kk];
        }
        __syncthreads();
        #pragma unroll
        for (int kk = 0; kk < TK; ++kk) {
            float av[4], wv[4];
            #pragma unroll
            for (int rr = 0; rr < 4; ++rr) av[rr] = a_lds[rg * 4 + rr][kk];
            #pragma unroll
            for (int g = 0; g < 4; ++g) wv[g] = w_lds[g][jl][kk];
            #pragma unroll
            for (int rr = 0; rr < 4; ++rr)
                #pragma unroll
                for (int g = 0; g < 4; ++g)
                    acc[rr][g] = fmaf(av[rr], wv[g], acc[rr][g]);
        }
        __syncthreads();
    }
}

// One LSTM timestep for one layer, fused GEMM(s) + cell.
// gates = hprev@Whh^T + xin@Wih^T + bih + bhh ; cell -> cout, hout
// xdim == HH: xin is [BB,HH] (layer1, full staged GEMM)
// xdim == XD0: xin is [BB,3] (layer0, tiny epilogue dot)
__global__ __launch_bounds__(256)
void lstm_step(const float* __restrict__ hprev,
               const float* __restrict__ xin, const int xdim,
               const float* __restrict__ Whh, const float* __restrict__ Wih,
               const float* __restrict__ bih, const float* __restrict__ bhh,
               const float* __restrict__ cprev,
               float* __restrict__ cout, float* __restrict__ hout)
{
    __shared__ float a_lds[TM][TK + 1];
    __shared__ float w_lds[4][TN][TK + 1];

    const int t = threadIdx.x;
    const int jl = t & 31;
    const int rg = t >> 5;
    const int j0 = blockIdx.x * TN;
    const int r0 = blockIdx.y * TM;

    float acc[4][4];
    #pragma unroll
    for (int rr = 0; rr < 4; ++rr)
        #pragma unroll
        for (int g = 0; g < 4; ++g) acc[rr][g] = 0.0f;

    // recurrent part
    gemm_pass(hprev, Whh, r0, j0, t, acc, a_lds, w_lds);
    // input part
    if (xdim == HH) {
        gemm_pass(xin, Wih, r0, j0, t, acc, a_lds, w_lds);
    }

    const int j = j0 + jl;
    if (xdim == XD0) {
        // tiny input dot: 3 MACs per output
        #pragma unroll
        for (int rr = 0; rr < 4; ++rr) {
            int r = r0 + rg * 4 + rr;
            float x0 = xin[r * XD0 + 0];
            float x1 = xin[r * XD0 + 1];
            float x2 = xin[r * XD0 + 2];
            #pragma unroll
            for (int g = 0; g < 4; ++g) {
                const float* wr = &Wih[(size_t)(g * HH + j) * XD0];
                acc[rr][g] += x0 * wr[0] + x1 * wr[1] + x2 * wr[2];
            }
        }
    }

    // biases
    float bsum[4];
    #pragma unroll
    for (int g = 0; g < 4; ++g) bsum[g] = bih[g * HH + j] + bhh[g * HH + j];

    // LSTM cell (gate order: i, f, g, o)
    #pragma unroll
    for (int rr = 0; rr < 4; ++rr) {
        int r = r0 + rg * 4 + rr;
        float ig = sigmoid_(acc[rr][0] + bsum[0]);
        float fg = sigmoid_(acc[rr][1] + bsum[1]);
        float gg = tanh_(acc[rr][2] + bsum[2]);
        float og = sigmoid_(acc[rr][3] + bsum[3]);
        float cp = cprev[(size_t)r * HH + j];
        float cn = fg * cp + ig * gg;
        float hn = og * tanh_(cn);
        cout[(size_t)r * HH + j] = cn;
        hout[(size_t)r * HH + j] = hn;
    }
}

// td[b][s] = btd[s] + cat(h0T,h1T)[b][:] . Wtd[s][:]   (K = 1024)
__global__ __launch_bounds__(256)
void td_kernel(const float* __restrict__ h0T, const float* __restrict__ h1T,
               const float* __restrict__ Wtd, const float* __restrict__ btd,
               float* __restrict__ td)
{
    __shared__ float a_lds[TM][TK + 1];
    __shared__ float b_lds[TN][TK + 1];
    const int t = threadIdx.x;
    const int nl = t & 31;
    const int mq = t >> 5;
    const int n0 = blockIdx.x * TN;   // s tile
    const int m0 = blockIdx.y * TM;   // batch tile
    float acc[4] = {0.f, 0.f, 0.f, 0.f};

    for (int k0 = 0; k0 < 2 * HH; k0 += TK) {
        const float* src = (k0 < HH) ? h0T : h1T;
        int kb = k0 & (HH - 1);
        #pragma unroll
        for (int i = 0; i < (TM * TK) / 256; ++i) {
            int idx = t + i * 256;
            int r = idx >> 5, kk = idx & 31;
            a_lds[r][kk] = src[(size_t)(m0 + r) * HH + kb + kk];
        }
        #pragma unroll
        for (int i = 0; i < (TN * TK) / 256; ++i) {
            int idx = t + i * 256;
            int jn = idx >> 5, kk = idx & 31;
            b_lds[jn][kk] = Wtd[(size_t)(n0 + jn) * (2 * HH) + k0 + kk];
        }
        __syncthreads();
        #pragma unroll
        for (int kk = 0; kk < TK; ++kk) {
            float bv = b_lds[nl][kk];
            #pragma unroll
            for (int rr = 0; rr < 4; ++rr)
                acc[rr] = fmaf(a_lds[mq * 4 + rr][kk], bv, acc[rr]);
        }
        __syncthreads();
    }
    #pragma unroll
    for (int rr = 0; rr < 4; ++rr)
        td[(size_t)(m0 + mq * 4 + rr) * TDN + n0 + nl] = acc[rr] + btd[n0 + nl];
}

// fc1 = relu(td @ Wfc1^T + bfc1); out = fc1 @ Wfc2^T + bfc2
__global__ __launch_bounds__(256)
void fc_kernel(const float* __restrict__ td,
               const float* __restrict__ Wfc1, const float* __restrict__ bfc1,
               const float* __restrict__ Wfc2, const float* __restrict__ bfc2,
               float* __restrict__ out)
{
    __shared__ float td_lds[32][TDN];
    __shared__ float f1_lds[32][FC1N];
    const int t = threadIdx.x;
    const int r0 = blockIdx.x * 32;

    #pragma unroll
    for (int i = 0; i < (32 * TDN) / 256; ++i) {
        int idx = t + i * 256;
        int r = idx >> 8, k = idx & 255;
        td_lds[r][k] = td[(size_t)(r0 + r) * TDN + k];
    }
    __syncthreads();

    for (int idx = t; idx < 32 * FC1N; idx += 256) {
        int r = idx / FC1N, o = idx % FC1N;
        float s = bfc1[o];
        for (int k = 0; k < TDN; ++k) s = fmaf(td_lds[r][k], Wfc1[o * TDN + k], s);
        f1_lds[r][o] = fmaxf(s, 0.0f);
    }
    __syncthreads();

    for (int idx = t; idx < 32 * OUTN; idx += 256) {
        int r = idx / OUTN, o = idx % OUTN;
        float s = bfc2[o];
        for (int k = 0; k < FC1N; ++k) s = fmaf(f1_lds[r][k], Wfc2[o * FC1N + k], s);
        out[(size_t)(r0 + r) * OUTN + o] = s;
    }
}

extern "C" void kernel_launch(void* const* d_in, const int* in_sizes, int n_in,
                              void* d_out, int out_size, void* d_ws, size_t ws_size,
                              hipStream_t stream)
{
    const float* x    = (const float*)d_in[0];   // [256,512,3]
    const float* h0   = (const float*)d_in[1];   // [2,512,512]
    const float* c0   = (const float*)d_in[2];   // [2,512,512]
    const float* Wih0 = (const float*)d_in[3];   // [2048,3]
    const float* Whh0 = (const float*)d_in[4];   // [2048,512]
    const float* bih0 = (const float*)d_in[5];
    const float* bhh0 = (const float*)d_in[6];
    const float* Wih1 = (const float*)d_in[7];   // [2048,512]
    const float* Whh1 = (const float*)d_in[8];   // [2048,512]
    const float* bih1 = (const float*)d_in[9];
    const float* bhh1 = (const float*)d_in[10];
    const float* Wtd  = (const float*)d_in[11];  // [256,1024]
    const float* btd  = (const float*)d_in[12];
    const float* Wfc1 = (const float*)d_in[13];  // [20,256]
    const float* bfc1 = (const float*)d_in[14];
    const float* Wfc2 = (const float*)d_in[15];  // [2,20]
    const float* bfc2 = (const float*)d_in[16];
    float* out = (float*)d_out;

    const size_t NBH = (size_t)BB * HH;
    float* ws  = (float*)d_ws;
    float* H0a = ws;            // layer0 h ping
    float* H0b = H0a + NBH;     // layer0 h pong
    float* C0b = H0b + NBH;     // layer0 c (in-place after t=0)
    float* H1a = C0b + NBH;
    float* H1b = H1a + NBH;
    float* C1b = H1b + NBH;
    float* TD  = C1b + NBH;     // [512,256]

    dim3 blk(256);
    dim3 grid(HH / TN, BB / TM);   // 16 x 16 = 256 blocks

    for (int ts = 0; ts < SS; ++ts) {
        // layer 0: write idx (ts+1)&1  -> ts even writes H0b, odd writes H0a
        const float* h0p = (ts == 0) ? h0 : ((ts & 1) ? H0b : H0a);
        float*       h0n = (ts & 1) ? H0a : H0b;
        const float* c0p = (ts == 0) ? c0 : C0b;
        lstm_step<<<grid, blk, 0, stream>>>(h0p, x + (size_t)ts * BB * XD0, XD0,
                                            Whh0, Wih0, bih0, bhh0, c0p, C0b, h0n);
        // layer 1: input is h0n (y0 at step ts)
        const float* h1p = (ts == 0) ? (h0 + NBH) : ((ts & 1) ? H1b : H1a);
        float*       h1n = (ts & 1) ? H1a : H1b;
        const float* c1p = (ts == 0) ? (c0 + NBH) : C1b;
        lstm_step<<<grid, blk, 0, stream>>>(h1p, h0n, HH,
                                            Whh1, Wih1, bih1, bhh1, c1p, C1b, h1n);
    }
    // SS=256 even -> final states in H0a / H1a
    dim3 gtd(TDN / TN, BB / TM);   // 8 x 16
    td_kernel<<<gtd, blk, 0, stream>>>(H0a, H1a, Wtd, btd, TD);
    fc_kernel<<<dim3(BB / 32), blk, 0, stream>>>(TD, Wfc1, bfc1, Wfc2, bfc2, out);

    (void)in_sizes; (void)n_in; (void)out_size; (void)ws_size;
}

// Round 2
// 8606.911 us; speedup vs baseline: 5.6320x; 5.6320x over previous
//
#include <hip/hip_runtime.h>
#include <math.h>

// Problem dims
#define BB 512
#define HH 512
#define SS 256
#define XD0 3
#define TDN 256
#define FC1N 20
#define OUTN 2

// head tiles (validated round 1)
#define TM 32
#define TN 32
#define TK 32

#define LDP 40   // padded LDS row length in shorts (80B rows -> ~2-way banks, free)

typedef __attribute__((ext_vector_type(8))) short short8;
typedef __attribute__((ext_vector_type(4))) float f32x4;

__device__ __forceinline__ unsigned short bf16_rne(float f) {
    unsigned u = __float_as_uint(f);
    u += 0x7FFFu + ((u >> 16) & 1u);
    return (unsigned short)(u >> 16);
}
__device__ __forceinline__ float bf16_to_f(unsigned short h) {
    return __uint_as_float(((unsigned)h) << 16);
}
__device__ __forceinline__ float sigmoid_(float x) { return 1.0f / (1.0f + __expf(-x)); }
__device__ __forceinline__ float tanh_(float x) {
    float e = __expf(2.0f * x);
    return 1.0f - 2.0f / (e + 1.0f);
}

// fp32 -> (bf16 hi, bf16 lo) split conversion
__global__ __launch_bounds__(256)
void cvt_hilo(const float* __restrict__ in, short* __restrict__ hi,
              short* __restrict__ lo, int n)
{
    int i = blockIdx.x * 256 + threadIdx.x;
    if (i < n) {
        float v = in[i];
        unsigned short h = bf16_rne(v);
        hi[i] = (short)h;
        lo[i] = (short)bf16_rne(v - bf16_to_f(h));
    }
}

// Fused LSTM step, MFMA split-bf16.
// Block tile: 64 batch rows x 16 hidden units x 4 gates.
// grid = (HH/16, BB/64) = (32, 8); 256 threads = 4 waves, wave w owns rows w*16..w*16+15.
// XMODE=0: layer0 (x-part = 3-wide fp32 dot in epilogue)
// XMODE=1: layer1 (x-part = second K=512 MFMA pass over Wih)
template<int XMODE>
__global__ __launch_bounds__(256)
void lstm_step_mfma(
    const short* __restrict__ h_hi, const short* __restrict__ h_lo,   // [BB][HH]
    const short* __restrict__ x_hi, const short* __restrict__ x_lo,   // layer1 only
    const float* __restrict__ xf,                                     // layer0 only [BB][3]
    const short* __restrict__ Whh_hi, const short* __restrict__ Whh_lo, // [4H][H]
    const short* __restrict__ Wih_hi, const short* __restrict__ Wih_lo, // layer1 only
    const float* __restrict__ Wih0,                                   // layer0 only [4H][3]
    const float* __restrict__ bih, const float* __restrict__ bhh,
    const float* __restrict__ cprev, float* __restrict__ cout,
    float* __restrict__ houtf, short* __restrict__ hout_hi, short* __restrict__ hout_lo)
{
    __shared__ __align__(16) short sAh[64 * LDP];
    __shared__ __align__(16) short sAl[64 * LDP];
    __shared__ __align__(16) short sBh[4 * 16 * LDP];
    __shared__ __align__(16) short sBl[4 * 16 * LDP];

    const int t = threadIdx.x;
    const int w = t >> 6;
    const int l = t & 63;
    const int j0 = blockIdx.x * 16;   // hidden-unit tile
    const int r0 = blockIdx.y * 64;   // batch-row tile

    // staging decomposition
    const int sr  = t >> 2;          // A row 0..63
    const int skq = t & 3;           // A k-quad (8 shorts each)
    const int bg  = t >> 6;          // B gate 0..3
    const int bjj = (t >> 2) & 15;   // B hidden unit 0..15
    const int bkq = t & 3;           // B k-quad

    const int NK = XMODE ? 32 : 16;  // K-steps of 32 (layer1: h pass + x pass)

    f32x4 acc[4];
    #pragma unroll
    for (int g = 0; g < 4; ++g)
        #pragma unroll
        for (int q = 0; q < 4; ++q) acc[g][q] = 0.0f;

    // register prefetch of tile ks=0
    short8 pAh, pAl, pBh, pBl;
    {
        pAh = *(const short8*)&h_hi[(size_t)(r0 + sr) * HH + skq * 8];
        pAl = *(const short8*)&h_lo[(size_t)(r0 + sr) * HH + skq * 8];
        pBh = *(const short8*)&Whh_hi[(size_t)(bg * HH + j0 + bjj) * HH + bkq * 8];
        pBl = *(const short8*)&Whh_lo[(size_t)(bg * HH + j0 + bjj) * HH + bkq * 8];
    }

    for (int ks = 0; ks < NK; ++ks) {
        __syncthreads();  // previous compute done before overwrite
        *(short8*)&sAh[sr * LDP + skq * 8] = pAh;
        *(short8*)&sAl[sr * LDP + skq * 8] = pAl;
        *(short8*)&sBh[(bg * 16 + bjj) * LDP + bkq * 8] = pBh;
        *(short8*)&sBl[(bg * 16 + bjj) * LDP + bkq * 8] = pBl;
        __syncthreads();

        // prefetch next K-tile (global latency hides under MFMA below)
        if (ks + 1 < NK) {
            const int kn = ks + 1;
            const short *Ah, *Al, *Wh, *Wl;
            if (XMODE && kn >= 16) { Ah = x_hi; Al = x_lo; Wh = Wih_hi; Wl = Wih_lo; }
            else                   { Ah = h_hi; Al = h_lo; Wh = Whh_hi; Wl = Whh_lo; }
            const int k0 = (kn & 15) * 32;
            pAh = *(const short8*)&Ah[(size_t)(r0 + sr) * HH + k0 + skq * 8];
            pAl = *(const short8*)&Al[(size_t)(r0 + sr) * HH + k0 + skq * 8];
            pBh = *(const short8*)&Wh[(size_t)(bg * HH + j0 + bjj) * HH + k0 + bkq * 8];
            pBl = *(const short8*)&Wl[(size_t)(bg * HH + j0 + bjj) * HH + k0 + bkq * 8];
        }

        // compute: wave w, rows w*16+(l&15); same lane->(idx&15, kchunk) scheme for A and B
        const int ar = (w * 16 + (l & 15)) * LDP + (l >> 4) * 8;
        short8 a_h = *(const short8*)&sAh[ar];
        short8 a_l = *(const short8*)&sAl[ar];
        #pragma unroll
        for (int g = 0; g < 4; ++g) {
            const int br = (g * 16 + (l & 15)) * LDP + (l >> 4) * 8;
            short8 b_h = *(const short8*)&sBh[br];
            short8 b_l = *(const short8*)&sBl[br];
            acc[g] = __builtin_amdgcn_mfma_f32_16x16x32_bf16(a_h, b_h, acc[g], 0, 0, 0);
            acc[g] = __builtin_amdgcn_mfma_f32_16x16x32_bf16(a_h, b_l, acc[g], 0, 0, 0);
            acc[g] = __builtin_amdgcn_mfma_f32_16x16x32_bf16(a_l, b_h, acc[g], 0, 0, 0);
        }
    }

    // epilogue: fused LSTM cell. C/D frag: col=lane&15 (hidden unit), row=(lane>>4)*4+reg (batch)
    const int j = j0 + (l & 15);
    float bs[4];
    #pragma unroll
    for (int g = 0; g < 4; ++g) bs[g] = bih[g * HH + j] + bhh[g * HH + j];

    const int rb = r0 + w * 16 + ((l >> 4) << 2);
    #pragma unroll
    for (int q = 0; q < 4; ++q) {
        const int r = rb + q;
        float gi = acc[0][q] + bs[0];
        float gf = acc[1][q] + bs[1];
        float gg = acc[2][q] + bs[2];
        float go = acc[3][q] + bs[3];
        if (XMODE == 0) {
            const float x0 = xf[r * XD0 + 0];
            const float x1 = xf[r * XD0 + 1];
            const float x2 = xf[r * XD0 + 2];
            gi += x0 * Wih0[(0 * HH + j) * XD0 + 0] + x1 * Wih0[(0 * HH + j) * XD0 + 1] + x2 * Wih0[(0 * HH + j) * XD0 + 2];
            gf += x0 * Wih0[(1 * HH + j) * XD0 + 0] + x1 * Wih0[(1 * HH + j) * XD0 + 1] + x2 * Wih0[(1 * HH + j) * XD0 + 2];
            gg += x0 * Wih0[(2 * HH + j) * XD0 + 0] + x1 * Wih0[(2 * HH + j) * XD0 + 1] + x2 * Wih0[(2 * HH + j) * XD0 + 2];
            go += x0 * Wih0[(3 * HH + j) * XD0 + 0] + x1 * Wih0[(3 * HH + j) * XD0 + 1] + x2 * Wih0[(3 * HH + j) * XD0 + 2];
        }
        const float I = sigmoid_(gi);
        const float F = sigmoid_(gf);
        const float G = tanh_(gg);
        const float O = sigmoid_(go);
        const float cp = cprev[(size_t)r * HH + j];
        const float cn = F * cp + I * G;
        const float hn = O * tanh_(cn);
        cout[(size_t)r * HH + j]  = cn;
        houtf[(size_t)r * HH + j] = hn;
        const unsigned short hb = bf16_rne(hn);
        hout_hi[(size_t)r * HH + j] = (short)hb;
        hout_lo[(size_t)r * HH + j] = (short)bf16_rne(hn - bf16_to_f(hb));
    }
}

// td[b][s] = btd[s] + cat(h0T,h1T)[b][:] . Wtd[s][:]   (validated round 1)
__global__ __launch_bounds__(256)
void td_kernel(const float* __restrict__ h0T, const float* __restrict__ h1T,
               const float* __restrict__ Wtd, const float* __restrict__ btd,
               float* __restrict__ td)
{
    __shared__ float a_lds[TM][TK + 1];
    __shared__ float b_lds[TN][TK + 1];
    const int t = threadIdx.x;
    const int nl = t & 31;
    const int mq = t >> 5;
    const int n0 = blockIdx.x * TN;
    const int m0 = blockIdx.y * TM;
    float acc[4] = {0.f, 0.f, 0.f, 0.f};

    for (int k0 = 0; k0 < 2 * HH; k0 += TK) {
        const float* src = (k0 < HH) ? h0T : h1T;
        int kb = k0 & (HH - 1);
        #pragma unroll
        for (int i = 0; i < (TM * TK) / 256; ++i) {
            int idx = t + i * 256;
            int r = idx >> 5, kk = idx & 31;
            a_lds[r][kk] = src[(size_t)(m0 + r) * HH + kb + kk];
        }
        #pragma unroll
        for (int i = 0; i < (TN * TK) / 256; ++i) {
            int idx = t + i * 256;
            int jn = idx >> 5, kk = idx & 31;
            b_lds[jn][kk] = Wtd[(size_t)(n0 + jn) * (2 * HH) + k0 + kk];
        }
        __syncthreads();
        #pragma unroll
        for (int kk = 0; kk < TK; ++kk) {
            float bv = b_lds[nl][kk];
            #pragma unroll
            for (int rr = 0; rr < 4; ++rr)
                acc[rr] = fmaf(a_lds[mq * 4 + rr][kk], bv, acc[rr]);
        }
        __syncthreads();
    }
    #pragma unroll
    for (int rr = 0; rr < 4; ++rr)
        td[(size_t)(m0 + mq * 4 + rr) * TDN + n0 + nl] = acc[rr] + btd[n0 + nl];
}

__global__ __launch_bounds__(256)
void fc_kernel(const float* __restrict__ td,
               const float* __restrict__ Wfc1, const float* __restrict__ bfc1,
               const float* __restrict__ Wfc2, const float* __restrict__ bfc2,
               float* __restrict__ out)
{
    __shared__ float td_lds[32][TDN];
    __shared__ float f1_lds[32][FC1N];
    const int t = threadIdx.x;
    const int r0 = blockIdx.x * 32;

    #pragma unroll
    for (int i = 0; i < (32 * TDN) / 256; ++i) {
        int idx = t + i * 256;
        int r = idx >> 8, k = idx & 255;
        td_lds[r][k] = td[(size_t)(r0 + r) * TDN + k];
    }
    __syncthreads();

    for (int idx = t; idx < 32 * FC1N; idx += 256) {
        int r = idx / FC1N, o = idx % FC1N;
        float s = bfc1[o];
        for (int k = 0; k < TDN; ++k) s = fmaf(td_lds[r][k], Wfc1[o * TDN + k], s);
        f1_lds[r][o] = fmaxf(s, 0.0f);
    }
    __syncthreads();

    for (int idx = t; idx < 32 * OUTN; idx += 256) {
        int r = idx / OUTN, o = idx % OUTN;
        float s = bfc2[o];
        for (int k = 0; k < FC1N; ++k) s = fmaf(f1_lds[r][k], Wfc2[o * FC1N + k], s);
        out[(size_t)(r0 + r) * OUTN + o] = s;
    }
}

extern "C" void kernel_launch(void* const* d_in, const int* in_sizes, int n_in,
                              void* d_out, int out_size, void* d_ws, size_t ws_size,
                              hipStream_t stream)
{
    const float* x    = (const float*)d_in[0];
    const float* h0   = (const float*)d_in[1];
    const float* c0   = (const float*)d_in[2];
    const float* Wih0 = (const float*)d_in[3];
    const float* Whh0 = (const float*)d_in[4];
    const float* bih0 = (const float*)d_in[5];
    const float* bhh0 = (const float*)d_in[6];
    const float* Wih1 = (const float*)d_in[7];
    const float* Whh1 = (const float*)d_in[8];
    const float* bih1 = (const float*)d_in[9];
    const float* bhh1 = (const float*)d_in[10];
    const float* Wtd  = (const float*)d_in[11];
    const float* btd  = (const float*)d_in[12];
    const float* Wfc1 = (const float*)d_in[13];
    const float* bfc1 = (const float*)d_in[14];
    const float* Wfc2 = (const float*)d_in[15];
    const float* bfc2 = (const float*)d_in[16];
    float* out = (float*)d_out;

    const size_t WSZ = (size_t)4 * HH * HH;   // 2048*512 weight elems
    const size_t HSZ = (size_t)BB * HH;       // 512*512 state elems

    // workspace layout (bytes)
    char* p = (char*)d_ws;
    short* Whh0_hi = (short*)p;              p += WSZ * 2;
    short* Whh0_lo = (short*)p;              p += WSZ * 2;
    short* Whh1_hi = (short*)p;              p += WSZ * 2;
    short* Whh1_lo = (short*)p;              p += WSZ * 2;
    short* Wih1_hi = (short*)p;              p += WSZ * 2;
    short* Wih1_lo = (short*)p;              p += WSZ * 2;
    short* H0hi[2]; short* H0lo[2]; short* H1hi[2]; short* H1lo[2];
    H0hi[0] = (short*)p; p += HSZ * 2;  H0lo[0] = (short*)p; p += HSZ * 2;
    H0hi[1] = (short*)p; p += HSZ * 2;  H0lo[1] = (short*)p; p += HSZ * 2;
    H1hi[0] = (short*)p; p += HSZ * 2;  H1lo[0] = (short*)p; p += HSZ * 2;
    H1hi[1] = (short*)p; p += HSZ * 2;  H1lo[1] = (short*)p; p += HSZ * 2;
    float* C0  = (float*)p; p += HSZ * 4;
    float* C1  = (float*)p; p += HSZ * 4;
    float* H0f = (float*)p; p += HSZ * 4;
    float* H1f = (float*)p; p += HSZ * 4;
    float* TD  = (float*)p; p += (size_t)BB * TDN * 4;

    // split-convert weights + initial h (every call; no static state)
    cvt_hilo<<<dim3((int)(WSZ / 256)), dim3(256), 0, stream>>>(Whh0, Whh0_hi, Whh0_lo, (int)WSZ);
    cvt_hilo<<<dim3((int)(WSZ / 256)), dim3(256), 0, stream>>>(Whh1, Whh1_hi, Whh1_lo, (int)WSZ);
    cvt_hilo<<<dim3((int)(WSZ / 256)), dim3(256), 0, stream>>>(Wih1, Wih1_hi, Wih1_lo, (int)WSZ);
    cvt_hilo<<<dim3((int)(HSZ / 256)), dim3(256), 0, stream>>>(h0,        H0hi[0], H0lo[0], (int)HSZ);
    cvt_hilo<<<dim3((int)(HSZ / 256)), dim3(256), 0, stream>>>(h0 + HSZ,  H1hi[0], H1lo[0], (int)HSZ);

    const dim3 sgrid(HH / 16, BB / 64);   // 32 x 8
    const dim3 blk(256);

    for (int ts = 0; ts < SS; ++ts) {
        const int cur = ts & 1, nxt = cur ^ 1;
        lstm_step_mfma<0><<<sgrid, blk, 0, stream>>>(
            H0hi[cur], H0lo[cur], nullptr, nullptr, x + (size_t)ts * BB * XD0,
            Whh0_hi, Whh0_lo, nullptr, nullptr, Wih0,
            bih0, bhh0, (ts == 0) ? c0 : C0, C0,
            H0f, H0hi[nxt], H0lo[nxt]);
        lstm_step_mfma<1><<<sgrid, blk, 0, stream>>>(
            H1hi[cur], H1lo[cur], H0hi[nxt], H0lo[nxt], nullptr,
            Whh1_hi, Whh1_lo, Wih1_hi, Wih1_lo, nullptr,
            bih1, bhh1, (ts == 0) ? (c0 + HSZ) : C1, C1,
            H1f, H1hi[nxt], H1lo[nxt]);
    }

    const dim3 gtd(TDN / TN, BB / TM);
    td_kernel<<<gtd, blk, 0, stream>>>(H0f, H1f, Wtd, btd, TD);
    fc_kernel<<<dim3(BB / 32), blk, 0, stream>>>(TD, Wfc1, bfc1, Wfc2, bfc2, out);

    (void)in_sizes; (void)n_in; (void)out_size; (void)ws_size;
}